// Round 3
// baseline (378.362 us; speedup 1.0000x reference)
//
#include <hip/hip_runtime.h>
#include <stdint.h>
#include <type_traits>

// ---------------- problem constants ----------------
#define CIN   256
#define COUT  256
#define HH    56
#define WW    56
#define HW    3136          // 56*56
#define BATCH 32
#define NPIX  (BATCH*HW)    // 100352 = 784 * 128 exactly
#define PH    58
#define PW    58
#define PPIX  (PH*PW)       // 3364
#define KTOT  2304          // 9 taps * 256 cin
#define BKB   128           // K-block in bytes (i8 elems) = half a tap
#define NKIT  (KTOT/BKB)    // 18

typedef int8_t  i8;
typedef int     intx4  __attribute__((ext_vector_type(4)));
typedef int8_t  i8x16  __attribute__((ext_vector_type(16)));
typedef short   short8 __attribute__((ext_vector_type(8)));
typedef float   floatx4 __attribute__((ext_vector_type(4)));

// -------- global->LDS 16B async copy (offset arg MUST be 0: it shifts the
// LDS destination too — see IntrinsicsAMDGPU.td; R4 failed on this) ---------
__device__ __forceinline__ void gload_lds16(const i8* g, void* lds_base) {
    __builtin_amdgcn_global_load_lds(
        (const __attribute__((address_space(1))) void*)g,
        (__attribute__((address_space(3))) void*)lds_base,
        16, 0, 0);
}

// ---------------------------------------------------------------------------
// Kernel 1: weight prep. scale[o]=mean|w[o]|; wg[o][t*256+i]=sign(w) as int8.
// Also zero-inits BN-stat accumulators (ws is poisoned each launch).
// ---------------------------------------------------------------------------
__global__ __launch_bounds__(256) void prep_w(const float* __restrict__ w,
                                              i8* __restrict__ wg,
                                              float* __restrict__ scale,
                                              float* __restrict__ bnsum,
                                              float* __restrict__ bnsumsq) {
    int o = blockIdx.x;
    int i = threadIdx.x;
    const float* wrow = w + (size_t)o * KTOT + (size_t)i * 9;   // OIHW
    float asum = 0.f;
#pragma unroll
    for (int t = 0; t < 9; ++t) {
        float v = wrow[t];
        asum += fabsf(v);
        wg[(size_t)o * KTOT + t * CIN + i] = (v > 0.f) ? (i8)1 : ((v < 0.f) ? (i8)(-1) : (i8)0);
    }
    for (int off = 32; off > 0; off >>= 1) asum += __shfl_down(asum, off);
    __shared__ float red[4];
    if ((threadIdx.x & 63) == 0) red[threadIdx.x >> 6] = asum;
    __syncthreads();
    if (threadIdx.x == 0) {
        scale[o]   = (red[0] + red[1] + red[2] + red[3]) * (1.f / (float)KTOT);
        bnsum[o]   = 0.f;
        bnsumsq[o] = 0.f;
    }
}

// ---------------------------------------------------------------------------
// Kernel 2: zero the 1-pixel border of the padded NHWC int8 sign tensor.
// ---------------------------------------------------------------------------
__global__ __launch_bounds__(256) void zero_border(i8* __restrict__ xs) {
    int n  = blockIdx.x / PH;
    int pr = blockIdx.x % PH;
    int* row = (int*)(xs + ((size_t)n * PPIX + (size_t)pr * PW) * CIN);
    if (pr == 0 || pr == PH - 1) {
        for (int idx = threadIdx.x; idx < PW * CIN / 4; idx += 256) row[idx] = 0;
    } else {
        if (threadIdx.x < 64)       row[threadIdx.x] = 0;                       // col 0
        else if (threadIdx.x < 128) row[(PW - 1) * (CIN / 4) + threadIdx.x - 64] = 0; // col 57
    }
}

// ---------------------------------------------------------------------------
// Kernel 3: binarize + NCHW->padded-NHWC transpose, int8 out.
// grid (49, 4, 32): 64-pixel x 64-cin tiles. Dword-packed LDS, stride 17.
// R2: float4 global loads (16B/lane, G13), 4x fewer VMEM instructions.
// ---------------------------------------------------------------------------
__global__ __launch_bounds__(256) void binarize(const float* __restrict__ x,
                                                i8* __restrict__ xs) {
    __shared__ int lds[64 * 17];   // [pix][cinquad], stride 17 dwords
    int p0 = blockIdx.x * 64;
    int c0 = blockIdx.y * 64;
    int n  = blockIdx.z;
    const float* xin = x + (size_t)n * CIN * HW;
    int t  = threadIdx.x;
    int pq = t & 15;               // pixel quad 0..15 (4 consecutive pixels)
    int cq = t >> 4;               // channel quad 0..15 (4 consecutive channels)
    floatx4 f[4];
#pragma unroll
    for (int r = 0; r < 4; ++r)
        f[r] = *(const floatx4*)&xin[(size_t)(c0 + cq * 4 + r) * HW + p0 + pq * 4];
#pragma unroll
    for (int j = 0; j < 4; ++j) {
        int packed = 0;
#pragma unroll
        for (int r = 0; r < 4; ++r) {
            float v = f[r][j];
            int s = (v > 0.f) ? 1 : ((v < 0.f) ? -1 : 0);
            packed |= (s & 0xff) << (8 * r);
        }
        lds[(pq * 4 + j) * 17 + cq] = packed;
    }
    __syncthreads();
    int cch = t & 3;                           // 16-byte chunk 0..3
    int pi  = t >> 2;                          // pixel 0..63
    int4 v;
    v.x = lds[pi * 17 + cch * 4 + 0];
    v.y = lds[pi * 17 + cch * 4 + 1];
    v.z = lds[pi * 17 + cch * 4 + 2];
    v.w = lds[pi * 17 + cch * 4 + 3];
    int p = p0 + pi;
    int h = p / WW, w = p - (p / WW) * WW;
    *(int4*)&xs[((size_t)n * PPIX + (size_t)(h + 1) * PW + (w + 1)) * CIN
                + c0 + cch * 16] = v;
}

// ---------------------------------------------------------------------------
// Kernel 4: binary conv implicit GEMM, i8 MFMA K=64, BK=128B.
// R3: B (wg, 0.59 MB, L2-resident) is NO LONGER STAGED THROUGH LDS — each
// wave loads its B fragments directly from global (16 rows x 64B per instr,
// all L2 hits; 4 precomputed base pointers, imm offsets <= 2240). This:
//   - halves LDS traffic (A-only staging + A-only ds_reads)
//   - shrinks LDS 64 KB -> 32 KB (2 x 16 KB A double-buffer) -> 3-4 blocks/CU
//     (was 2), restoring cross-block latency hiding at each barrier drain
//   - removes B-side bank conflicts
// A path unchanged: double-buffered, XOR-swizzled, gload_lds16, one
// __syncthreads per K-iter. Epilogue yt (32 KB) exactly reuses smem.
// ---------------------------------------------------------------------------
__global__ __launch_bounds__(256, 3) void conv_gemm(const i8* __restrict__ xs,
                                                    const i8* __restrict__ wg,
                                                    short* __restrict__ y,
                                                    float* __restrict__ bnsum,
                                                    float* __restrict__ bnsumsq) {
    __shared__ __align__(16) i8 smem[32768];   // A dbuf: buf b at b*16384

    int tid  = threadIdx.x;
    int lane = tid & 63;
    int wv   = tid >> 6;
    int wm   = wv & 1;        // wave row (pixels)
    int wn   = wv >> 1;       // wave col (couts)
    int mt   = blockIdx.x;
    int nt   = blockIdx.y;

    // ---- A staging source pointers (XOR-swizzled 16B chunk within 128B row) --
    int prow = tid >> 3;
    int koff = ((tid ^ (tid >> 3)) & 7) * 16;
    const i8* aP[4];
#pragma unroll
    for (int j = 0; j < 4; ++j) {
        int P = mt * 128 + prow + 32 * j;     // global pixel
        int n = P / HW;
        int p = P - n * HW;
        int h = p / WW;
        int w = p - h * WW;
        aP[j] = xs + ((size_t)n * PPIX + (size_t)h * PW + w) * CIN + koff;
    }
    i8* aD[2][4];
#pragma unroll
    for (int b = 0; b < 2; ++b)
#pragma unroll
        for (int j = 0; j < 4; ++j)
            aD[b][j] = smem + b * 16384 + j * 4096 + wv * 1024;

    // ---- A fragment read pointers (buffer 0; buffer 1 = +16384) ----
    int l7  = lane & 7;
    int l15 = lane & 15;
    int lhi = lane >> 4;
    int sw0 = ((lhi ^ l7) << 4);              // kk=0 swizzled chunk offset
    int sw1 = sw0 ^ 0x40;                     // kk=1
    const i8* Ard0 = smem + (wm * 64 + l15) * BKB + sw0;
    const i8* Ard1 = smem + (wm * 64 + l15) * BKB + sw1;

    // ---- B fragment global base pointers (no swizzle, no LDS) ----
    // frag for (in, kk, kb): lane reads wg[(nt*128+wn*64+in*16+l15)*KTOT
    //                                     + kb + kk*64 + lhi*16]
    const i8* Bg[4];
#pragma unroll
    for (int in = 0; in < 4; ++in)
        Bg[in] = wg + (size_t)(nt * 128 + wn * 64 + in * 16 + l15) * KTOT + lhi * 16;

    intx4 acc[4][4];
#pragma unroll
    for (int im = 0; im < 4; ++im)
#pragma unroll
        for (int in = 0; in < 4; ++in) acc[im][in] = intx4{0, 0, 0, 0};

    // ---- prologue: stage A k=0 into buffer 0 ----
#pragma unroll
    for (int j = 0; j < 4; ++j) gload_lds16(aP[j], aD[0][j]);
    __syncthreads();

    auto stage = [&](auto KBC) {
        constexpr int KB  = (int)decltype(KBC)::value;
        constexpr int cur = KB & 1;
        constexpr int kb  = KB * BKB;          // imm-offset friendly (<= 2176)
        // B fragments for THIS iter: issue first (oldest in vmcnt order)
        intx4 bf0[4], bf1[4];
#pragma unroll
        for (int in = 0; in < 4; ++in) bf0[in] = *(const intx4*)(Bg[in] + kb);
#pragma unroll
        for (int in = 0; in < 4; ++in) bf1[in] = *(const intx4*)(Bg[in] + kb + 64);
        // A stage for next iter
        if constexpr (KB < NKIT - 1) {
            constexpr int nb  = KB + 1;
            constexpr int nxt = nb & 1;
            constexpr int ao  = (nb / 6) * PW * CIN + (nb % 6) * 128;  // tap row/col
#pragma unroll
            for (int j = 0; j < 4; ++j) gload_lds16(aP[j] + ao, aD[nxt][j]);
        }
        constexpr int bufo = cur * 16384;
        intx4 af0[4], af1[4];
#pragma unroll
        for (int im = 0; im < 4; ++im) af0[im] = *(const intx4*)(Ard0 + bufo + im * 2048);
#pragma unroll
        for (int im = 0; im < 4; ++im) af1[im] = *(const intx4*)(Ard1 + bufo + im * 2048);
#pragma unroll
        for (int im = 0; im < 4; ++im)
#pragma unroll
            for (int in = 0; in < 4; ++in)
                acc[im][in] = __builtin_amdgcn_mfma_i32_16x16x64_i8(
                    af0[im], bf0[in], acc[im][in], 0, 0, 0);
#pragma unroll
        for (int im = 0; im < 4; ++im)
#pragma unroll
            for (int in = 0; in < 4; ++in)
                acc[im][in] = __builtin_amdgcn_mfma_i32_16x16x64_i8(
                    af1[im], bf1[in], acc[im][in], 0, 0, 0);
        __syncthreads();
    };
#define ST(k) stage(std::integral_constant<int, k>{});
    ST(0) ST(1) ST(2) ST(3) ST(4) ST(5) ST(6) ST(7) ST(8)
    ST(9) ST(10) ST(11) ST(12) ST(13) ST(14) ST(15) ST(16) ST(17)
#undef ST

    // ---- epilogue: BN stats from regs + coalesced store via LDS transpose ----
    int colBase = nt * 128 + wn * 64 + l15;            // global cout
    short* yt = (short*)smem;                          // 128 x 128 int16, 32 KB
#pragma unroll
    for (int in = 0; in < 4; ++in) {
        int o = colBase + in * 16;
        float s1 = 0.f, s2 = 0.f;
#pragma unroll
        for (int im = 0; im < 4; ++im) {
            int r0 = wm * 64 + im * 16 + lhi * 4;      // local pixel row
#pragma unroll
            for (int rg = 0; rg < 4; ++rg) {
                int vi = acc[im][in][rg];              // exact integer count
                yt[(r0 + rg) * 128 + wn * 64 + in * 16 + l15] = (short)vi;
                float v = (float)vi;
                s1 += v;
                s2 += v * v;
            }
        }
        s1 += __shfl_xor(s1, 16); s2 += __shfl_xor(s2, 16);
        s1 += __shfl_xor(s1, 32); s2 += __shfl_xor(s2, 32);
        if (lhi == 0) {
            atomicAdd(&bnsum[o], s1);
            atomicAdd(&bnsumsq[o], s2);
        }
    }
    __syncthreads();
    // coalesced NHWC stores: 16 threads x 16B = one 128-cout half-row
#pragma unroll
    for (int pass = 0; pass < 8; ++pass) {
        int p = (tid >> 4) + 16 * pass;
        int c = tid & 15;
        *(short8*)&y[(size_t)(mt * 128 + p) * COUT + nt * 128 + c * 8] =
            *(const short8*)&yt[p * 128 + c * 8];
    }
}

// ---------------------------------------------------------------------------
// Kernel 5: fold BN into per-channel (g, c): out = relu(g*s + c)
// ---------------------------------------------------------------------------
__global__ void coeff(const float* __restrict__ bnsum, const float* __restrict__ bnsumsq,
                      const float* __restrict__ scale, const float* __restrict__ gamma,
                      const float* __restrict__ beta, float* __restrict__ kg,
                      float* __restrict__ kc) {
    int o = threadIdx.x;
    float mean = bnsum[o] * (1.f / (float)NPIX);
    float var  = fmaxf(bnsumsq[o] * (1.f / (float)NPIX) - mean * mean, 0.f);
    float sc   = scale[o];
    float inv  = rsqrtf(sc * sc * var + 1e-5f);
    float g    = gamma[o] * sc * inv;
    kg[o] = g;
    kc[o] = beta[o] - mean * g;
}

// ---------------------------------------------------------------------------
// Kernel 6: int16 NHWC -> fp32 NCHW transpose + affine + relu.
// ---------------------------------------------------------------------------
__global__ __launch_bounds__(256) void bn_out(const short* __restrict__ y,
                                              const float* __restrict__ kg,
                                              const float* __restrict__ kc,
                                              float* __restrict__ out) {
    __shared__ float lds[64 * 65];   // [pix][ch], stride 65
    int p0 = blockIdx.x * 64;
    int o0 = blockIdx.y * 64;
    int n  = blockIdx.z;
    int t  = threadIdx.x;
    int cch = t & 7;
    float g[8], c[8];
#pragma unroll
    for (int e = 0; e < 8; ++e) {
        g[e] = kg[o0 + cch * 8 + e];
        c[e] = kc[o0 + cch * 8 + e];
    }
    const short* yb = y + ((size_t)n * HW + p0) * COUT + o0;
#pragma unroll
    for (int j = 0; j < 2; ++j) {
        int pi = (t >> 3) + 32 * j;
        short8 sv = *(const short8*)&yb[(size_t)pi * COUT + cch * 8];
#pragma unroll
        for (int e = 0; e < 8; ++e)
            lds[pi * 65 + cch * 8 + e] = fmaxf(g[e] * (float)sv[e] + c[e], 0.f);
    }
    __syncthreads();
    float* ob = out + ((size_t)n * COUT + o0) * HW + p0;
    int pq = t & 15;       // 16 float4 = 64 pixels
    int ch = t >> 4;       // 16 channels per round
#pragma unroll
    for (int r = 0; r < 4; ++r) {
        int cr = ch + 16 * r;
        floatx4 v;
#pragma unroll
        for (int e = 0; e < 4; ++e) v[e] = lds[(pq * 4 + e) * 65 + cr];
        *(floatx4*)&ob[(size_t)cr * HW + pq * 4] = v;
    }
}

// ---------------------------------------------------------------------------
extern "C" void kernel_launch(void* const* d_in, const int* in_sizes, int n_in,
                              void* d_out, int out_size, void* d_ws, size_t ws_size,
                              hipStream_t stream) {
    const float* x     = (const float*)d_in[0];   // [32,256,56,56]
    const float* w     = (const float*)d_in[1];   // [256,256,3,3]
    const float* gamma = (const float*)d_in[2];   // [256]
    const float* beta  = (const float*)d_in[3];   // [256]
    float* out = (float*)d_out;

    char* ws = (char*)d_ws;
    size_t off = 0;
    i8* xs = (i8*)(ws + off);    off += (size_t)BATCH * PPIX * CIN;                // 27.6 MB
    i8* wg = (i8*)(ws + off);    off += (size_t)COUT * KTOT;                       // 0.59 MB
    short* y = (short*)(ws + off); off += (size_t)NPIX * COUT * sizeof(short);     // 51.4 MB
    float* scale   = (float*)(ws + off); off += 1024;
    float* bnsum   = (float*)(ws + off); off += 1024;
    float* bnsumsq = (float*)(ws + off); off += 1024;
    float* kg      = (float*)(ws + off); off += 1024;
    float* kc      = (float*)(ws + off); off += 1024;

    hipLaunchKernelGGL(prep_w, dim3(COUT), dim3(256), 0, stream, w, wg, scale, bnsum, bnsumsq);
    hipLaunchKernelGGL(zero_border, dim3(BATCH * PH), dim3(256), 0, stream, xs);
    hipLaunchKernelGGL(binarize, dim3(HW / 64, CIN / 64, BATCH), dim3(256), 0, stream, x, xs);
    hipLaunchKernelGGL(conv_gemm, dim3(NPIX / 128, 2), dim3(256), 0, stream,
                       xs, wg, y, bnsum, bnsumsq);
    hipLaunchKernelGGL(coeff, dim3(1), dim3(256), 0, stream,
                       bnsum, bnsumsq, scale, gamma, beta, kg, kc);
    hipLaunchKernelGGL(bn_out, dim3(HW / 64, COUT / 64, BATCH), dim3(256), 0, stream,
                       y, kg, kc, out);
}

// Round 4
// 276.632 us; speedup vs baseline: 1.3677x; 1.3677x over previous
//
#include <hip/hip_runtime.h>
#include <stdint.h>
#include <type_traits>

// ---------------- problem constants ----------------
#define CIN   256
#define COUT  256
#define HH    56
#define WW    56
#define HW    3136          // 56*56
#define BATCH 32
#define NPIX  (BATCH*HW)    // 100352 = 784 * 128 exactly
#define PH    58
#define PW    58
#define PPIX  (PH*PW)       // 3364
#define KTOT  2304          // 9 taps * 256 cin
#define BKB   128           // K-block in bytes (i8 elems) = half a tap
#define NKIT  (KTOT/BKB)    // 18

typedef int8_t  i8;
typedef int     intx4  __attribute__((ext_vector_type(4)));
typedef int8_t  i8x16  __attribute__((ext_vector_type(16)));
typedef short   short8 __attribute__((ext_vector_type(8)));
typedef float   floatx4 __attribute__((ext_vector_type(4)));

// -------- global->LDS 16B async copy (offset arg MUST be 0: it shifts the
// LDS destination too — see IntrinsicsAMDGPU.td) ----------------------------
__device__ __forceinline__ void gload_lds16(const i8* g, void* lds_base) {
    __builtin_amdgcn_global_load_lds(
        (const __attribute__((address_space(1))) void*)g,
        (__attribute__((address_space(3))) void*)lds_base,
        16, 0, 0);
}

// ---------------------------------------------------------------------------
// Kernel 1 (fused): blocks [0,COUT): weight prep (scale, sign-weights, BN
// accumulator zero-init). blocks [COUT, COUT+BATCH*PH): zero the 1-pixel
// border of the padded NHWC int8 sign tensor. R4: fused to cut a launch.
// ---------------------------------------------------------------------------
__global__ __launch_bounds__(256) void prep_zero(const float* __restrict__ w,
                                                 i8* __restrict__ wg,
                                                 float* __restrict__ scale,
                                                 float* __restrict__ bnsum,
                                                 float* __restrict__ bnsumsq,
                                                 i8* __restrict__ xs) {
    int b = blockIdx.x;
    if (b < COUT) {
        int o = b;
        int i = threadIdx.x;
        const float* wrow = w + (size_t)o * KTOT + (size_t)i * 9;   // OIHW
        float asum = 0.f;
#pragma unroll
        for (int t = 0; t < 9; ++t) {
            float v = wrow[t];
            asum += fabsf(v);
            wg[(size_t)o * KTOT + t * CIN + i] = (v > 0.f) ? (i8)1 : ((v < 0.f) ? (i8)(-1) : (i8)0);
        }
        for (int off = 32; off > 0; off >>= 1) asum += __shfl_down(asum, off);
        __shared__ float red[4];
        if ((threadIdx.x & 63) == 0) red[threadIdx.x >> 6] = asum;
        __syncthreads();
        if (threadIdx.x == 0) {
            scale[o]   = (red[0] + red[1] + red[2] + red[3]) * (1.f / (float)KTOT);
            bnsum[o]   = 0.f;
            bnsumsq[o] = 0.f;
        }
    } else {
        int bb = b - COUT;
        int n  = bb / PH;
        int pr = bb % PH;
        int* row = (int*)(xs + ((size_t)n * PPIX + (size_t)pr * PW) * CIN);
        if (pr == 0 || pr == PH - 1) {
            for (int idx = threadIdx.x; idx < PW * CIN / 4; idx += 256) row[idx] = 0;
        } else {
            if (threadIdx.x < 64)       row[threadIdx.x] = 0;                       // col 0
            else if (threadIdx.x < 128) row[(PW - 1) * (CIN / 4) + threadIdx.x - 64] = 0; // col 57
        }
    }
}

// ---------------------------------------------------------------------------
// Kernel 2: binarize + NCHW->padded-NHWC transpose, int8 out.
// grid (49, 4, 32): 64-pixel x 64-cin tiles. Dword-packed LDS, stride 17.
// R2: float4 global loads (16B/lane, G13), 4x fewer VMEM instructions.
// ---------------------------------------------------------------------------
__global__ __launch_bounds__(256) void binarize(const float* __restrict__ x,
                                                i8* __restrict__ xs) {
    __shared__ int lds[64 * 17];   // [pix][cinquad], stride 17 dwords
    int p0 = blockIdx.x * 64;
    int c0 = blockIdx.y * 64;
    int n  = blockIdx.z;
    const float* xin = x + (size_t)n * CIN * HW;
    int t  = threadIdx.x;
    int pq = t & 15;               // pixel quad 0..15 (4 consecutive pixels)
    int cq = t >> 4;               // channel quad 0..15 (4 consecutive channels)
    floatx4 f[4];
#pragma unroll
    for (int r = 0; r < 4; ++r)
        f[r] = *(const floatx4*)&xin[(size_t)(c0 + cq * 4 + r) * HW + p0 + pq * 4];
#pragma unroll
    for (int j = 0; j < 4; ++j) {
        int packed = 0;
#pragma unroll
        for (int r = 0; r < 4; ++r) {
            float v = f[r][j];
            int s = (v > 0.f) ? 1 : ((v < 0.f) ? -1 : 0);
            packed |= (s & 0xff) << (8 * r);
        }
        lds[(pq * 4 + j) * 17 + cq] = packed;
    }
    __syncthreads();
    int cch = t & 3;                           // 16-byte chunk 0..3
    int pi  = t >> 2;                          // pixel 0..63
    int4 v;
    v.x = lds[pi * 17 + cch * 4 + 0];
    v.y = lds[pi * 17 + cch * 4 + 1];
    v.z = lds[pi * 17 + cch * 4 + 2];
    v.w = lds[pi * 17 + cch * 4 + 3];
    int p = p0 + pi;
    int h = p / WW, w = p - (p / WW) * WW;
    *(int4*)&xs[((size_t)n * PPIX + (size_t)(h + 1) * PW + (w + 1)) * CIN
                + c0 + cch * 16] = v;
}

// ---------------------------------------------------------------------------
// Kernel 3: binary conv implicit GEMM, i8 MFMA K=64, BK=128B.
// Body = the proven R0/R2 schedule (B staged in LDS, 2x32KB double-buffer,
// ONE __syncthreads per K-iter; barrier's vmcnt(0) drain only waits on loads
// issued a full compute phase earlier).
// R4 change: 1-D grid 1568 with pair-contiguous XCD mapping
//   mt = 8*(h>>4) + (h&7);  nt = (h>>3)&1
// so (mt,0) and (mt,1) — which read the IDENTICAL A-tile — land on the SAME
// XCD in consecutive rounds (h and h+8 are congruent mod 8). R3's FETCH_SIZE
// was exactly 2x xs: with grid (784,2) the pair was 784 dispatches apart and
// A was fetched from HBM twice. Predicted FETCH 54.6 -> ~30 MB.
// [R1 counted-vmcnt graft: -17%; R3 B-from-global: -40%. Schedule is a local
//  optimum — do not graft at the sync structure.]
// ---------------------------------------------------------------------------
__global__ __launch_bounds__(256, 2) void conv_gemm(const i8* __restrict__ xs,
                                                    const i8* __restrict__ wg,
                                                    short* __restrict__ y,
                                                    float* __restrict__ bnsum,
                                                    float* __restrict__ bnsumsq) {
    __shared__ __align__(16) i8 smem[65536];   // buf b: As at b*32768, Bs at +16384

    int tid  = threadIdx.x;
    int lane = tid & 63;
    int wv   = tid >> 6;
    int wm   = wv & 1;        // wave row (pixels)
    int wn   = wv >> 1;       // wave col (couts)
    int hb   = blockIdx.x;
    int mt   = ((hb >> 4) << 3) + (hb & 7);   // 0..783
    int nt   = (hb >> 3) & 1;                 // 0..1

    // ---- staging source pointers (XOR-swizzled 16B chunk within 128B row) ----
    int prow = tid >> 3;
    int koff = ((tid ^ (tid >> 3)) & 7) * 16;
    const i8* aP[4];
    const i8* bP[4];
#pragma unroll
    for (int j = 0; j < 4; ++j) {
        int P = mt * 128 + prow + 32 * j;     // global pixel
        int n = P / HW;
        int p = P - n * HW;
        int h = p / WW;
        int w = p - h * WW;
        aP[j] = xs + ((size_t)n * PPIX + (size_t)h * PW + w) * CIN + koff;
        int o = nt * 128 + prow + 32 * j;
        bP[j] = wg + (size_t)o * KTOT + koff;
    }
    i8* aD[2][4];
    i8* bD[2][4];
#pragma unroll
    for (int b = 0; b < 2; ++b)
#pragma unroll
        for (int j = 0; j < 4; ++j) {
            aD[b][j] = smem + b * 32768 + j * 4096 + wv * 1024;
            bD[b][j] = smem + b * 32768 + 16384 + j * 4096 + wv * 1024;
        }

    // ---- fragment read pointers (buffer 0; buffer 1 = +32768) ----
    int l7  = lane & 7;
    int l15 = lane & 15;
    int lhi = lane >> 4;
    int sw0 = ((lhi ^ l7) << 4);              // kk=0 swizzled chunk offset
    int sw1 = sw0 ^ 0x40;                     // kk=1
    const i8* Ard0 = smem + (wm * 64 + l15) * BKB + sw0;
    const i8* Ard1 = smem + (wm * 64 + l15) * BKB + sw1;
    const i8* Brd0 = smem + 16384 + (wn * 64 + l15) * BKB + sw0;
    const i8* Brd1 = smem + 16384 + (wn * 64 + l15) * BKB + sw1;

    intx4 acc[4][4];
#pragma unroll
    for (int im = 0; im < 4; ++im)
#pragma unroll
        for (int in = 0; in < 4; ++in) acc[im][in] = intx4{0, 0, 0, 0};

    // ---- prologue: stage k=0 into buffer 0 ----
#pragma unroll
    for (int j = 0; j < 4; ++j) gload_lds16(aP[j], aD[0][j]);
#pragma unroll
    for (int j = 0; j < 4; ++j) gload_lds16(bP[j], bD[0][j]);
    __syncthreads();

    auto stage = [&](auto KBC) {
        constexpr int KB  = (int)decltype(KBC)::value;
        constexpr int cur = KB & 1;
        if constexpr (KB < NKIT - 1) {
            constexpr int nb  = KB + 1;
            constexpr int nxt = nb & 1;
            constexpr int ao  = (nb / 6) * PW * CIN + (nb % 6) * 128;  // tap row/col
            constexpr int bo  = nb * BKB;
#pragma unroll
            for (int j = 0; j < 4; ++j) gload_lds16(aP[j] + ao, aD[nxt][j]);
#pragma unroll
            for (int j = 0; j < 4; ++j) gload_lds16(bP[j] + bo, bD[nxt][j]);
        }
        constexpr int bufo = cur * 32768;
        intx4 af0[4], bf0[4], af1[4], bf1[4];
#pragma unroll
        for (int im = 0; im < 4; ++im) af0[im] = *(const intx4*)(Ard0 + bufo + im * 2048);
#pragma unroll
        for (int in = 0; in < 4; ++in) bf0[in] = *(const intx4*)(Brd0 + bufo + in * 2048);
#pragma unroll
        for (int im = 0; im < 4; ++im) af1[im] = *(const intx4*)(Ard1 + bufo + im * 2048);
#pragma unroll
        for (int in = 0; in < 4; ++in) bf1[in] = *(const intx4*)(Brd1 + bufo + in * 2048);
#pragma unroll
        for (int im = 0; im < 4; ++im)
#pragma unroll
            for (int in = 0; in < 4; ++in)
                acc[im][in] = __builtin_amdgcn_mfma_i32_16x16x64_i8(
                    af0[im], bf0[in], acc[im][in], 0, 0, 0);
#pragma unroll
        for (int im = 0; im < 4; ++im)
#pragma unroll
            for (int in = 0; in < 4; ++in)
                acc[im][in] = __builtin_amdgcn_mfma_i32_16x16x64_i8(
                    af1[im], bf1[in], acc[im][in], 0, 0, 0);
        __syncthreads();
    };
#define ST(k) stage(std::integral_constant<int, k>{});
    ST(0) ST(1) ST(2) ST(3) ST(4) ST(5) ST(6) ST(7) ST(8)
    ST(9) ST(10) ST(11) ST(12) ST(13) ST(14) ST(15) ST(16) ST(17)
#undef ST

    // ---- epilogue: BN stats from regs + coalesced store via LDS transpose ----
    int colBase = nt * 128 + wn * 64 + l15;            // global cout
    short* yt = (short*)smem;                          // 128 x 128 int16, 32 KB
#pragma unroll
    for (int in = 0; in < 4; ++in) {
        int o = colBase + in * 16;
        float s1 = 0.f, s2 = 0.f;
#pragma unroll
        for (int im = 0; im < 4; ++im) {
            int r0 = wm * 64 + im * 16 + lhi * 4;      // local pixel row
#pragma unroll
            for (int rg = 0; rg < 4; ++rg) {
                int vi = acc[im][in][rg];              // exact integer count
                yt[(r0 + rg) * 128 + wn * 64 + in * 16 + l15] = (short)vi;
                float v = (float)vi;
                s1 += v;
                s2 += v * v;
            }
        }
        s1 += __shfl_xor(s1, 16); s2 += __shfl_xor(s2, 16);
        s1 += __shfl_xor(s1, 32); s2 += __shfl_xor(s2, 32);
        if (lhi == 0) {
            atomicAdd(&bnsum[o], s1);
            atomicAdd(&bnsumsq[o], s2);
        }
    }
    __syncthreads();
    // coalesced NHWC stores: 16 threads x 16B = one 128-cout half-row
#pragma unroll
    for (int pass = 0; pass < 8; ++pass) {
        int p = (tid >> 4) + 16 * pass;
        int c = tid & 15;
        *(short8*)&y[(size_t)(mt * 128 + p) * COUT + nt * 128 + c * 8] =
            *(const short8*)&yt[p * 128 + c * 8];
    }
}

// ---------------------------------------------------------------------------
// Kernel 4: int16 NHWC -> fp32 NCHW transpose + affine + relu.
// R4: BN-coefficient fold (old `coeff` kernel) fused in — each block computes
// its own 64 channels' (g, c) from bnsum/bnsumsq/scale/gamma/beta (64 rsqrt
// per block, redundant across pixel-blocks but trivially cheap). One fewer
// launch; math identical.
// ---------------------------------------------------------------------------
__global__ __launch_bounds__(256) void bn_out(const short* __restrict__ y,
                                              const float* __restrict__ bnsum,
                                              const float* __restrict__ bnsumsq,
                                              const float* __restrict__ scale,
                                              const float* __restrict__ gamma,
                                              const float* __restrict__ beta,
                                              float* __restrict__ out) {
    __shared__ float lds[64 * 65];   // [pix][ch], stride 65
    __shared__ float gs[64], cs[64];
    int p0 = blockIdx.x * 64;
    int o0 = blockIdx.y * 64;
    int n  = blockIdx.z;
    int t  = threadIdx.x;
    if (t < 64) {
        int o = o0 + t;
        float mean = bnsum[o] * (1.f / (float)NPIX);
        float var  = fmaxf(bnsumsq[o] * (1.f / (float)NPIX) - mean * mean, 0.f);
        float sc   = scale[o];
        float inv  = rsqrtf(sc * sc * var + 1e-5f);
        float g    = gamma[o] * sc * inv;
        gs[t] = g;
        cs[t] = beta[o] - mean * g;
    }
    __syncthreads();
    int cch = t & 7;
    float g[8], c[8];
#pragma unroll
    for (int e = 0; e < 8; ++e) {
        g[e] = gs[cch * 8 + e];
        c[e] = cs[cch * 8 + e];
    }
    const short* yb = y + ((size_t)n * HW + p0) * COUT + o0;
#pragma unroll
    for (int j = 0; j < 2; ++j) {
        int pi = (t >> 3) + 32 * j;
        short8 sv = *(const short8*)&yb[(size_t)pi * COUT + cch * 8];
#pragma unroll
        for (int e = 0; e < 8; ++e)
            lds[pi * 65 + cch * 8 + e] = fmaxf(g[e] * (float)sv[e] + c[e], 0.f);
    }
    __syncthreads();
    float* ob = out + ((size_t)n * COUT + o0) * HW + p0;
    int pq = t & 15;       // 16 float4 = 64 pixels
    int ch = t >> 4;       // 16 channels per round
#pragma unroll
    for (int r = 0; r < 4; ++r) {
        int cr = ch + 16 * r;
        floatx4 v;
#pragma unroll
        for (int e = 0; e < 4; ++e) v[e] = lds[(pq * 4 + e) * 65 + cr];
        *(floatx4*)&ob[(size_t)cr * HW + pq * 4] = v;
    }
}

// ---------------------------------------------------------------------------
extern "C" void kernel_launch(void* const* d_in, const int* in_sizes, int n_in,
                              void* d_out, int out_size, void* d_ws, size_t ws_size,
                              hipStream_t stream) {
    const float* x     = (const float*)d_in[0];   // [32,256,56,56]
    const float* w     = (const float*)d_in[1];   // [256,256,3,3]
    const float* gamma = (const float*)d_in[2];   // [256]
    const float* beta  = (const float*)d_in[3];   // [256]
    float* out = (float*)d_out;

    char* ws = (char*)d_ws;
    size_t off = 0;
    i8* xs = (i8*)(ws + off);    off += (size_t)BATCH * PPIX * CIN;                // 27.6 MB
    i8* wg = (i8*)(ws + off);    off += (size_t)COUT * KTOT;                       // 0.59 MB
    short* y = (short*)(ws + off); off += (size_t)NPIX * COUT * sizeof(short);     // 51.4 MB
    float* scale   = (float*)(ws + off); off += 1024;
    float* bnsum   = (float*)(ws + off); off += 1024;
    float* bnsumsq = (float*)(ws + off); off += 1024;

    hipLaunchKernelGGL(prep_zero, dim3(COUT + BATCH * PH), dim3(256), 0, stream,
                       w, wg, scale, bnsum, bnsumsq, xs);
    hipLaunchKernelGGL(binarize, dim3(HW / 64, CIN / 64, BATCH), dim3(256), 0, stream, x, xs);
    hipLaunchKernelGGL(conv_gemm, dim3(NPIX / 128 * 2), dim3(256), 0, stream,
                       xs, wg, y, bnsum, bnsumsq);
    hipLaunchKernelGGL(bn_out, dim3(HW / 64, COUT / 64, BATCH), dim3(256), 0, stream,
                       y, bnsum, bnsumsq, scale, gamma, beta, out);
}

// Round 5
// 276.297 us; speedup vs baseline: 1.3694x; 1.0012x over previous
//
#include <hip/hip_runtime.h>
#include <stdint.h>
#include <type_traits>

// ---------------- problem constants ----------------
#define CIN   256
#define COUT  256
#define HH    56
#define WW    56
#define HW    3136          // 56*56
#define BATCH 32
#define NPIX  (BATCH*HW)    // 100352 = 784 * 128 exactly
#define PH    58
#define PW    58
#define PPIX  (PH*PW)       // 3364
#define KTOT  2304          // 9 taps * 256 cin
#define BKB   128           // K-block in bytes (i8 elems) = half a tap
#define NKIT  (KTOT/BKB)    // 18

typedef int8_t  i8;
typedef int     intx4  __attribute__((ext_vector_type(4)));
typedef int8_t  i8x16  __attribute__((ext_vector_type(16)));
typedef short   short8 __attribute__((ext_vector_type(8)));
typedef float   floatx4 __attribute__((ext_vector_type(4)));

// -------- global->LDS 16B async copy (offset arg MUST be 0: it shifts the
// LDS destination too — see IntrinsicsAMDGPU.td) ----------------------------
__device__ __forceinline__ void gload_lds16(const i8* g, void* lds_base) {
    __builtin_amdgcn_global_load_lds(
        (const __attribute__((address_space(1))) void*)g,
        (__attribute__((address_space(3))) void*)lds_base,
        16, 0, 0);
}

// ---------------------------------------------------------------------------
// Kernel 1 (fused): blocks [0,COUT): weight prep (scale, sign-weights, BN
// accumulator zero-init). blocks [COUT, COUT+BATCH*PH): zero the 1-pixel
// border of the padded NHWC int8 sign tensor.
// ---------------------------------------------------------------------------
__global__ __launch_bounds__(256) void prep_zero(const float* __restrict__ w,
                                                 i8* __restrict__ wg,
                                                 float* __restrict__ scale,
                                                 float* __restrict__ bnsum,
                                                 float* __restrict__ bnsumsq,
                                                 i8* __restrict__ xs) {
    int b = blockIdx.x;
    if (b < COUT) {
        int o = b;
        int i = threadIdx.x;
        const float* wrow = w + (size_t)o * KTOT + (size_t)i * 9;   // OIHW
        float asum = 0.f;
#pragma unroll
        for (int t = 0; t < 9; ++t) {
            float v = wrow[t];
            asum += fabsf(v);
            wg[(size_t)o * KTOT + t * CIN + i] = (v > 0.f) ? (i8)1 : ((v < 0.f) ? (i8)(-1) : (i8)0);
        }
        for (int off = 32; off > 0; off >>= 1) asum += __shfl_down(asum, off);
        __shared__ float red[4];
        if ((threadIdx.x & 63) == 0) red[threadIdx.x >> 6] = asum;
        __syncthreads();
        if (threadIdx.x == 0) {
            scale[o]   = (red[0] + red[1] + red[2] + red[3]) * (1.f / (float)KTOT);
            bnsum[o]   = 0.f;
            bnsumsq[o] = 0.f;
        }
    } else {
        int bb = b - COUT;
        int n  = bb / PH;
        int pr = bb % PH;
        int* row = (int*)(xs + ((size_t)n * PPIX + (size_t)pr * PW) * CIN);
        if (pr == 0 || pr == PH - 1) {
            for (int idx = threadIdx.x; idx < PW * CIN / 4; idx += 256) row[idx] = 0;
        } else {
            if (threadIdx.x < 64)       row[threadIdx.x] = 0;                       // col 0
            else if (threadIdx.x < 128) row[(PW - 1) * (CIN / 4) + threadIdx.x - 64] = 0; // col 57
        }
    }
}

// ---------------------------------------------------------------------------
// Kernel 2: binarize + NCHW->padded-NHWC transpose, int8 out.
// R5: full-256-channel blocks, grid (49, 32) = 1568 blocks (was 6272 with
// 64-ch blocks). Why: old version wrote 64 B chunks at 256 B stride
// (sub-line partial writes) and had only 4 loads in flight per thread.
// Now: phase 1 does 16 float4 loads/thread (4 rounds x 4 channels), packing
// signs into dword LDS [64 pix][65] (64 dwords = all 256 ch per pixel);
// phase 2 emits FULL 256 B NHWC rows (16 lanes x int4 contiguous), ~1 KB
// contiguous per wave. All LDS patterns <=2-way bank aliasing (free, m136).
// Traffic identical; only granularity + per-thread MLP change.
// ---------------------------------------------------------------------------
__global__ __launch_bounds__(256) void binarize(const float* __restrict__ x,
                                                i8* __restrict__ xs) {
    __shared__ int lds[64 * 65];   // [pix][cinquad 0..63], stride 65 dwords
    int p0 = blockIdx.x * 64;
    int n  = blockIdx.y;
    const float* xin = x + (size_t)n * CIN * HW;
    int t   = threadIdx.x;
    int pq  = t & 15;              // pixel quad 0..15 (4 consecutive pixels)
    int cqg = t >> 4;              // channel-quad group 0..15
#pragma unroll
    for (int q = 0; q < 4; ++q) {
        int cbase = q * 64 + cqg * 4;      // 4 consecutive channels
        floatx4 f[4];
#pragma unroll
        for (int r = 0; r < 4; ++r)
            f[r] = *(const floatx4*)&xin[(size_t)(cbase + r) * HW + p0 + pq * 4];
#pragma unroll
        for (int j = 0; j < 4; ++j) {
            int packed = 0;
#pragma unroll
            for (int r = 0; r < 4; ++r) {
                float v = f[r][j];
                int s = (v > 0.f) ? 1 : ((v < 0.f) ? -1 : 0);
                packed |= (s & 0xff) << (8 * r);
            }
            lds[(pq * 4 + j) * 65 + q * 16 + cqg] = packed;
        }
    }
    __syncthreads();
    int ci = t & 15;               // 16-byte chunk 0..15 (full 256B row)
#pragma unroll
    for (int q = 0; q < 4; ++q) {
        int pi = (t >> 4) + q * 16;        // pixel 0..63
        int4 v;
        v.x = lds[pi * 65 + ci * 4 + 0];
        v.y = lds[pi * 65 + ci * 4 + 1];
        v.z = lds[pi * 65 + ci * 4 + 2];
        v.w = lds[pi * 65 + ci * 4 + 3];
        int p = p0 + pi;
        int h = p / WW, w = p - (p / WW) * WW;
        *(int4*)&xs[((size_t)n * PPIX + (size_t)(h + 1) * PW + (w + 1)) * CIN
                    + ci * 16] = v;
    }
}

// ---------------------------------------------------------------------------
// Kernel 3: binary conv implicit GEMM, i8 MFMA K=64, BK=128B.
// Proven R0/R2 schedule (B staged in LDS, 2x32KB double-buffer, ONE
// __syncthreads per K-iter) + R4's pair-contiguous XCD mapping
//   mt = 8*(h>>4) + (h&7);  nt = (h>>3)&1
// which halved FETCH_SIZE (54.6 -> 29.4 MB, verified): the (mt,0)/(mt,1)
// pair reading the identical A-tile lands on the same XCD in consecutive
// rounds -> A is an L2 hit the second time.
// [R1 counted-vmcnt graft: -17%; R3 B-from-global: -40%. Do not graft at
//  the sync structure.]
// ---------------------------------------------------------------------------
__global__ __launch_bounds__(256, 2) void conv_gemm(const i8* __restrict__ xs,
                                                    const i8* __restrict__ wg,
                                                    short* __restrict__ y,
                                                    float* __restrict__ bnsum,
                                                    float* __restrict__ bnsumsq) {
    __shared__ __align__(16) i8 smem[65536];   // buf b: As at b*32768, Bs at +16384

    int tid  = threadIdx.x;
    int lane = tid & 63;
    int wv   = tid >> 6;
    int wm   = wv & 1;        // wave row (pixels)
    int wn   = wv >> 1;       // wave col (couts)
    int hb   = blockIdx.x;
    int mt   = ((hb >> 4) << 3) + (hb & 7);   // 0..783
    int nt   = (hb >> 3) & 1;                 // 0..1

    // ---- staging source pointers (XOR-swizzled 16B chunk within 128B row) ----
    int prow = tid >> 3;
    int koff = ((tid ^ (tid >> 3)) & 7) * 16;
    const i8* aP[4];
    const i8* bP[4];
#pragma unroll
    for (int j = 0; j < 4; ++j) {
        int P = mt * 128 + prow + 32 * j;     // global pixel
        int n = P / HW;
        int p = P - n * HW;
        int h = p / WW;
        int w = p - h * WW;
        aP[j] = xs + ((size_t)n * PPIX + (size_t)h * PW + w) * CIN + koff;
        int o = nt * 128 + prow + 32 * j;
        bP[j] = wg + (size_t)o * KTOT + koff;
    }
    i8* aD[2][4];
    i8* bD[2][4];
#pragma unroll
    for (int b = 0; b < 2; ++b)
#pragma unroll
        for (int j = 0; j < 4; ++j) {
            aD[b][j] = smem + b * 32768 + j * 4096 + wv * 1024;
            bD[b][j] = smem + b * 32768 + 16384 + j * 4096 + wv * 1024;
        }

    // ---- fragment read pointers (buffer 0; buffer 1 = +32768) ----
    int l7  = lane & 7;
    int l15 = lane & 15;
    int lhi = lane >> 4;
    int sw0 = ((lhi ^ l7) << 4);              // kk=0 swizzled chunk offset
    int sw1 = sw0 ^ 0x40;                     // kk=1
    const i8* Ard0 = smem + (wm * 64 + l15) * BKB + sw0;
    const i8* Ard1 = smem + (wm * 64 + l15) * BKB + sw1;
    const i8* Brd0 = smem + 16384 + (wn * 64 + l15) * BKB + sw0;
    const i8* Brd1 = smem + 16384 + (wn * 64 + l15) * BKB + sw1;

    intx4 acc[4][4];
#pragma unroll
    for (int im = 0; im < 4; ++im)
#pragma unroll
        for (int in = 0; in < 4; ++in) acc[im][in] = intx4{0, 0, 0, 0};

    // ---- prologue: stage k=0 into buffer 0 ----
#pragma unroll
    for (int j = 0; j < 4; ++j) gload_lds16(aP[j], aD[0][j]);
#pragma unroll
    for (int j = 0; j < 4; ++j) gload_lds16(bP[j], bD[0][j]);
    __syncthreads();

    auto stage = [&](auto KBC) {
        constexpr int KB  = (int)decltype(KBC)::value;
        constexpr int cur = KB & 1;
        if constexpr (KB < NKIT - 1) {
            constexpr int nb  = KB + 1;
            constexpr int nxt = nb & 1;
            constexpr int ao  = (nb / 6) * PW * CIN + (nb % 6) * 128;  // tap row/col
            constexpr int bo  = nb * BKB;
#pragma unroll
            for (int j = 0; j < 4; ++j) gload_lds16(aP[j] + ao, aD[nxt][j]);
#pragma unroll
            for (int j = 0; j < 4; ++j) gload_lds16(bP[j] + bo, bD[nxt][j]);
        }
        constexpr int bufo = cur * 32768;
        intx4 af0[4], bf0[4], af1[4], bf1[4];
#pragma unroll
        for (int im = 0; im < 4; ++im) af0[im] = *(const intx4*)(Ard0 + bufo + im * 2048);
#pragma unroll
        for (int in = 0; in < 4; ++in) bf0[in] = *(const intx4*)(Brd0 + bufo + in * 2048);
#pragma unroll
        for (int im = 0; im < 4; ++im) af1[im] = *(const intx4*)(Ard1 + bufo + im * 2048);
#pragma unroll
        for (int in = 0; in < 4; ++in) bf1[in] = *(const intx4*)(Brd1 + bufo + in * 2048);
#pragma unroll
        for (int im = 0; im < 4; ++im)
#pragma unroll
            for (int in = 0; in < 4; ++in)
                acc[im][in] = __builtin_amdgcn_mfma_i32_16x16x64_i8(
                    af0[im], bf0[in], acc[im][in], 0, 0, 0);
#pragma unroll
        for (int im = 0; im < 4; ++im)
#pragma unroll
            for (int in = 0; in < 4; ++in)
                acc[im][in] = __builtin_amdgcn_mfma_i32_16x16x64_i8(
                    af1[im], bf1[in], acc[im][in], 0, 0, 0);
        __syncthreads();
    };
#define ST(k) stage(std::integral_constant<int, k>{});
    ST(0) ST(1) ST(2) ST(3) ST(4) ST(5) ST(6) ST(7) ST(8)
    ST(9) ST(10) ST(11) ST(12) ST(13) ST(14) ST(15) ST(16) ST(17)
#undef ST

    // ---- epilogue: BN stats from regs + coalesced store via LDS transpose ----
    int colBase = nt * 128 + wn * 64 + l15;            // global cout
    short* yt = (short*)smem;                          // 128 x 128 int16, 32 KB
#pragma unroll
    for (int in = 0; in < 4; ++in) {
        int o = colBase + in * 16;
        float s1 = 0.f, s2 = 0.f;
#pragma unroll
        for (int im = 0; im < 4; ++im) {
            int r0 = wm * 64 + im * 16 + lhi * 4;      // local pixel row
#pragma unroll
            for (int rg = 0; rg < 4; ++rg) {
                int vi = acc[im][in][rg];              // exact integer count
                yt[(r0 + rg) * 128 + wn * 64 + in * 16 + l15] = (short)vi;
                float v = (float)vi;
                s1 += v;
                s2 += v * v;
            }
        }
        s1 += __shfl_xor(s1, 16); s2 += __shfl_xor(s2, 16);
        s1 += __shfl_xor(s1, 32); s2 += __shfl_xor(s2, 32);
        if (lhi == 0) {
            atomicAdd(&bnsum[o], s1);
            atomicAdd(&bnsumsq[o], s2);
        }
    }
    __syncthreads();
    // coalesced NHWC stores: 16 threads x 16B = one 128-cout half-row
#pragma unroll
    for (int pass = 0; pass < 8; ++pass) {
        int p = (tid >> 4) + 16 * pass;
        int c = tid & 15;
        *(short8*)&y[(size_t)(mt * 128 + p) * COUT + nt * 128 + c * 8] =
            *(const short8*)&yt[p * 128 + c * 8];
    }
}

// ---------------------------------------------------------------------------
// Kernel 4: int16 NHWC -> fp32 NCHW transpose + affine + relu, with the BN
// coefficient fold fused in (per-block recompute of its 64 channels' g,c).
// ---------------------------------------------------------------------------
__global__ __launch_bounds__(256) void bn_out(const short* __restrict__ y,
                                              const float* __restrict__ bnsum,
                                              const float* __restrict__ bnsumsq,
                                              const float* __restrict__ scale,
                                              const float* __restrict__ gamma,
                                              const float* __restrict__ beta,
                                              float* __restrict__ out) {
    __shared__ float lds[64 * 65];   // [pix][ch], stride 65
    __shared__ float gs[64], cs[64];
    int p0 = blockIdx.x * 64;
    int o0 = blockIdx.y * 64;
    int n  = blockIdx.z;
    int t  = threadIdx.x;
    if (t < 64) {
        int o = o0 + t;
        float mean = bnsum[o] * (1.f / (float)NPIX);
        float var  = fmaxf(bnsumsq[o] * (1.f / (float)NPIX) - mean * mean, 0.f);
        float sc   = scale[o];
        float inv  = rsqrtf(sc * sc * var + 1e-5f);
        float g    = gamma[o] * sc * inv;
        gs[t] = g;
        cs[t] = beta[o] - mean * g;
    }
    __syncthreads();
    int cch = t & 7;
    float g[8], c[8];
#pragma unroll
    for (int e = 0; e < 8; ++e) {
        g[e] = gs[cch * 8 + e];
        c[e] = cs[cch * 8 + e];
    }
    const short* yb = y + ((size_t)n * HW + p0) * COUT + o0;
#pragma unroll
    for (int j = 0; j < 2; ++j) {
        int pi = (t >> 3) + 32 * j;
        short8 sv = *(const short8*)&yb[(size_t)pi * COUT + cch * 8];
#pragma unroll
        for (int e = 0; e < 8; ++e)
            lds[pi * 65 + cch * 8 + e] = fmaxf(g[e] * (float)sv[e] + c[e], 0.f);
    }
    __syncthreads();
    float* ob = out + ((size_t)n * COUT + o0) * HW + p0;
    int pq = t & 15;       // 16 float4 = 64 pixels
    int ch = t >> 4;       // 16 channels per round
#pragma unroll
    for (int r = 0; r < 4; ++r) {
        int cr = ch + 16 * r;
        floatx4 v;
#pragma unroll
        for (int e = 0; e < 4; ++e) v[e] = lds[(pq * 4 + e) * 65 + cr];
        *(floatx4*)&ob[(size_t)cr * HW + pq * 4] = v;
    }
}

// ---------------------------------------------------------------------------
extern "C" void kernel_launch(void* const* d_in, const int* in_sizes, int n_in,
                              void* d_out, int out_size, void* d_ws, size_t ws_size,
                              hipStream_t stream) {
    const float* x     = (const float*)d_in[0];   // [32,256,56,56]
    const float* w     = (const float*)d_in[1];   // [256,256,3,3]
    const float* gamma = (const float*)d_in[2];   // [256]
    const float* beta  = (const float*)d_in[3];   // [256]
    float* out = (float*)d_out;

    char* ws = (char*)d_ws;
    size_t off = 0;
    i8* xs = (i8*)(ws + off);    off += (size_t)BATCH * PPIX * CIN;                // 27.6 MB
    i8* wg = (i8*)(ws + off);    off += (size_t)COUT * KTOT;                       // 0.59 MB
    short* y = (short*)(ws + off); off += (size_t)NPIX * COUT * sizeof(short);     // 51.4 MB
    float* scale   = (float*)(ws + off); off += 1024;
    float* bnsum   = (float*)(ws + off); off += 1024;
    float* bnsumsq = (float*)(ws + off); off += 1024;

    hipLaunchKernelGGL(prep_zero, dim3(COUT + BATCH * PH), dim3(256), 0, stream,
                       w, wg, scale, bnsum, bnsumsq, xs);
    hipLaunchKernelGGL(binarize, dim3(HW / 64, BATCH), dim3(256), 0, stream, x, xs);
    hipLaunchKernelGGL(conv_gemm, dim3(NPIX / 128 * 2), dim3(256), 0, stream,
                       xs, wg, y, bnsum, bnsumsq);
    hipLaunchKernelGGL(bn_out, dim3(HW / 64, COUT / 64, BATCH), dim3(256), 0, stream,
                       y, bnsum, bnsumsq, scale, gamma, beta, out);
}

// Round 6
// 274.981 us; speedup vs baseline: 1.3760x; 1.0048x over previous
//
#include <hip/hip_runtime.h>
#include <stdint.h>
#include <type_traits>

// ---------------- problem constants ----------------
#define CIN   256
#define COUT  256
#define HH    56
#define WW    56
#define HW    3136          // 56*56
#define BATCH 32
#define NPIX  (BATCH*HW)    // 100352 = 784 * 128 exactly
#define PH    58
#define PW    58
#define PPIX  (PH*PW)       // 3364
#define KTOT  2304          // 9 taps * 256 cin
#define BKB   128           // K-block in bytes (i8 elems) = half a tap
#define NKIT  (KTOT/BKB)    // 18

#define NBIN  (HW/64*BATCH) // 1568 binarize blocks
#define NBRD  (BATCH*PH)    // 1856 border blocks

typedef int8_t  i8;
typedef int     intx4  __attribute__((ext_vector_type(4)));
typedef int8_t  i8x16  __attribute__((ext_vector_type(16)));
typedef short   short8 __attribute__((ext_vector_type(8)));
typedef float   floatx4 __attribute__((ext_vector_type(4)));

// -------- global->LDS 16B async copy (offset arg MUST be 0: it shifts the
// LDS destination too — see IntrinsicsAMDGPU.td) ----------------------------
__device__ __forceinline__ void gload_lds16(const i8* g, void* lds_base) {
    __builtin_amdgcn_global_load_lds(
        (const __attribute__((address_space(1))) void*)g,
        (__attribute__((address_space(3))) void*)lds_base,
        16, 0, 0);
}

// ---------------------------------------------------------------------------
// Kernel 1 (R6: fully fused front-end):
//   blocks [0, NBIN):            binarize + NCHW->padded-NHWC transpose
//   blocks [NBIN, NBIN+COUT):    weight prep + BN-acc zero-init
//   blocks [NBIN+COUT, +NBRD):   zero the 1-px border of xs
// Rationale: prep/border blocks are latency-bound (scalar loads, tiny
// writes); running them CONCURRENTLY with binarize's BW-bound blocks hides
// their cost under the memory stream instead of serializing a launch.
// ---------------------------------------------------------------------------
__global__ __launch_bounds__(256) void front(const float* __restrict__ x,
                                             const float* __restrict__ w,
                                             i8* __restrict__ xs,
                                             i8* __restrict__ wg,
                                             float* __restrict__ scale,
                                             float* __restrict__ bnsum,
                                             float* __restrict__ bnsumsq) {
    int b = blockIdx.x;
    int t = threadIdx.x;
    if (b < NBIN) {
        // ---- binarize (R5 body, verified neutral-at-floor) ----
        __shared__ int lds[64 * 65];   // [pix][cinquad 0..63], stride 65 dwords
        int p0 = (b % 49) * 64;
        int n  = b / 49;
        const float* xin = x + (size_t)n * CIN * HW;
        int pq  = t & 15;              // pixel quad (4 consecutive pixels)
        int cqg = t >> 4;              // channel-quad group 0..15
#pragma unroll
        for (int q = 0; q < 4; ++q) {
            int cbase = q * 64 + cqg * 4;
            floatx4 f[4];
#pragma unroll
            for (int r = 0; r < 4; ++r)
                f[r] = *(const floatx4*)&xin[(size_t)(cbase + r) * HW + p0 + pq * 4];
#pragma unroll
            for (int j = 0; j < 4; ++j) {
                int packed = 0;
#pragma unroll
                for (int r = 0; r < 4; ++r) {
                    float v = f[r][j];
                    int s = (v > 0.f) ? 1 : ((v < 0.f) ? -1 : 0);
                    packed |= (s & 0xff) << (8 * r);
                }
                lds[(pq * 4 + j) * 65 + q * 16 + cqg] = packed;
            }
        }
        __syncthreads();
        int ci = t & 15;               // 16-byte chunk (full 256B row)
#pragma unroll
        for (int q = 0; q < 4; ++q) {
            int pi = (t >> 4) + q * 16;
            int4 v;
            v.x = lds[pi * 65 + ci * 4 + 0];
            v.y = lds[pi * 65 + ci * 4 + 1];
            v.z = lds[pi * 65 + ci * 4 + 2];
            v.w = lds[pi * 65 + ci * 4 + 3];
            int p = p0 + pi;
            int h = p / WW, ww = p - (p / WW) * WW;
            *(int4*)&xs[((size_t)n * PPIX + (size_t)(h + 1) * PW + (ww + 1)) * CIN
                        + ci * 16] = v;
        }
    } else if (b < NBIN + COUT) {
        // ---- weight prep ----
        int o = b - NBIN;
        const float* wrow = w + (size_t)o * KTOT + (size_t)t * 9;   // OIHW
        float asum = 0.f;
#pragma unroll
        for (int tt = 0; tt < 9; ++tt) {
            float v = wrow[tt];
            asum += fabsf(v);
            wg[(size_t)o * KTOT + tt * CIN + t] = (v > 0.f) ? (i8)1 : ((v < 0.f) ? (i8)(-1) : (i8)0);
        }
        for (int off = 32; off > 0; off >>= 1) asum += __shfl_down(asum, off);
        __shared__ float red[4];
        if ((t & 63) == 0) red[t >> 6] = asum;
        __syncthreads();
        if (t == 0) {
            scale[o]   = (red[0] + red[1] + red[2] + red[3]) * (1.f / (float)KTOT);
            bnsum[o]   = 0.f;
            bnsumsq[o] = 0.f;
        }
    } else {
        // ---- border zero ----
        int bb = b - NBIN - COUT;
        int n  = bb / PH;
        int pr = bb % PH;
        int* row = (int*)(xs + ((size_t)n * PPIX + (size_t)pr * PW) * CIN);
        if (pr == 0 || pr == PH - 1) {
            for (int idx = t; idx < PW * CIN / 4; idx += 256) row[idx] = 0;
        } else {
            if (t < 64)       row[t] = 0;                                   // col 0
            else if (t < 128) row[(PW - 1) * (CIN / 4) + t - 64] = 0;       // col 57
        }
    }
}

// ---------------------------------------------------------------------------
// Kernel 2: binary conv implicit GEMM, i8 MFMA K=64, BK=128B.
// Proven R0/R2 schedule (B staged in LDS, 2x32KB double-buffer, ONE
// __syncthreads per K-iter) + R4's pair-contiguous XCD mapping
//   mt = 8*(h>>4) + (h&7);  nt = (h>>3)&1
// which halved FETCH_SIZE (54.6 -> 29.4 MB, verified): the (mt,0)/(mt,1)
// pair reading the identical A-tile lands on the same XCD in consecutive
// rounds -> A is an L2 hit the second time.
// [R1 counted-vmcnt graft: -17%; R3 B-from-global: -40%. Do not graft at
//  the sync structure.]
// ---------------------------------------------------------------------------
__global__ __launch_bounds__(256, 2) void conv_gemm(const i8* __restrict__ xs,
                                                    const i8* __restrict__ wg,
                                                    short* __restrict__ y,
                                                    float* __restrict__ bnsum,
                                                    float* __restrict__ bnsumsq) {
    __shared__ __align__(16) i8 smem[65536];   // buf b: As at b*32768, Bs at +16384

    int tid  = threadIdx.x;
    int lane = tid & 63;
    int wv   = tid >> 6;
    int wm   = wv & 1;        // wave row (pixels)
    int wn   = wv >> 1;       // wave col (couts)
    int hb   = blockIdx.x;
    int mt   = ((hb >> 4) << 3) + (hb & 7);   // 0..783
    int nt   = (hb >> 3) & 1;                 // 0..1

    // ---- staging source pointers (XOR-swizzled 16B chunk within 128B row) ----
    int prow = tid >> 3;
    int koff = ((tid ^ (tid >> 3)) & 7) * 16;
    const i8* aP[4];
    const i8* bP[4];
#pragma unroll
    for (int j = 0; j < 4; ++j) {
        int P = mt * 128 + prow + 32 * j;     // global pixel
        int n = P / HW;
        int p = P - n * HW;
        int h = p / WW;
        int w = p - h * WW;
        aP[j] = xs + ((size_t)n * PPIX + (size_t)h * PW + w) * CIN + koff;
        int o = nt * 128 + prow + 32 * j;
        bP[j] = wg + (size_t)o * KTOT + koff;
    }
    i8* aD[2][4];
    i8* bD[2][4];
#pragma unroll
    for (int b = 0; b < 2; ++b)
#pragma unroll
        for (int j = 0; j < 4; ++j) {
            aD[b][j] = smem + b * 32768 + j * 4096 + wv * 1024;
            bD[b][j] = smem + b * 32768 + 16384 + j * 4096 + wv * 1024;
        }

    // ---- fragment read pointers (buffer 0; buffer 1 = +32768) ----
    int l7  = lane & 7;
    int l15 = lane & 15;
    int lhi = lane >> 4;
    int sw0 = ((lhi ^ l7) << 4);              // kk=0 swizzled chunk offset
    int sw1 = sw0 ^ 0x40;                     // kk=1
    const i8* Ard0 = smem + (wm * 64 + l15) * BKB + sw0;
    const i8* Ard1 = smem + (wm * 64 + l15) * BKB + sw1;
    const i8* Brd0 = smem + 16384 + (wn * 64 + l15) * BKB + sw0;
    const i8* Brd1 = smem + 16384 + (wn * 64 + l15) * BKB + sw1;

    intx4 acc[4][4];
#pragma unroll
    for (int im = 0; im < 4; ++im)
#pragma unroll
        for (int in = 0; in < 4; ++in) acc[im][in] = intx4{0, 0, 0, 0};

    // ---- prologue: stage k=0 into buffer 0 ----
#pragma unroll
    for (int j = 0; j < 4; ++j) gload_lds16(aP[j], aD[0][j]);
#pragma unroll
    for (int j = 0; j < 4; ++j) gload_lds16(bP[j], bD[0][j]);
    __syncthreads();

    auto stage = [&](auto KBC) {
        constexpr int KB  = (int)decltype(KBC)::value;
        constexpr int cur = KB & 1;
        if constexpr (KB < NKIT - 1) {
            constexpr int nb  = KB + 1;
            constexpr int nxt = nb & 1;
            constexpr int ao  = (nb / 6) * PW * CIN + (nb % 6) * 128;  // tap row/col
            constexpr int bo  = nb * BKB;
#pragma unroll
            for (int j = 0; j < 4; ++j) gload_lds16(aP[j] + ao, aD[nxt][j]);
#pragma unroll
            for (int j = 0; j < 4; ++j) gload_lds16(bP[j] + bo, bD[nxt][j]);
        }
        constexpr int bufo = cur * 32768;
        intx4 af0[4], bf0[4], af1[4], bf1[4];
#pragma unroll
        for (int im = 0; im < 4; ++im) af0[im] = *(const intx4*)(Ard0 + bufo + im * 2048);
#pragma unroll
        for (int in = 0; in < 4; ++in) bf0[in] = *(const intx4*)(Brd0 + bufo + in * 2048);
#pragma unroll
        for (int im = 0; im < 4; ++im) af1[im] = *(const intx4*)(Ard1 + bufo + im * 2048);
#pragma unroll
        for (int in = 0; in < 4; ++in) bf1[in] = *(const intx4*)(Brd1 + bufo + in * 2048);
#pragma unroll
        for (int im = 0; im < 4; ++im)
#pragma unroll
            for (int in = 0; in < 4; ++in)
                acc[im][in] = __builtin_amdgcn_mfma_i32_16x16x64_i8(
                    af0[im], bf0[in], acc[im][in], 0, 0, 0);
#pragma unroll
        for (int im = 0; im < 4; ++im)
#pragma unroll
            for (int in = 0; in < 4; ++in)
                acc[im][in] = __builtin_amdgcn_mfma_i32_16x16x64_i8(
                    af1[im], bf1[in], acc[im][in], 0, 0, 0);
        __syncthreads();
    };
#define ST(k) stage(std::integral_constant<int, k>{});
    ST(0) ST(1) ST(2) ST(3) ST(4) ST(5) ST(6) ST(7) ST(8)
    ST(9) ST(10) ST(11) ST(12) ST(13) ST(14) ST(15) ST(16) ST(17)
#undef ST

    // ---- epilogue: BN stats from regs + coalesced store via LDS transpose ----
    int colBase = nt * 128 + wn * 64 + l15;            // global cout
    short* yt = (short*)smem;                          // 128 x 128 int16, 32 KB
#pragma unroll
    for (int in = 0; in < 4; ++in) {
        int o = colBase + in * 16;
        float s1 = 0.f, s2 = 0.f;
#pragma unroll
        for (int im = 0; im < 4; ++im) {
            int r0 = wm * 64 + im * 16 + lhi * 4;      // local pixel row
#pragma unroll
            for (int rg = 0; rg < 4; ++rg) {
                int vi = acc[im][in][rg];              // exact integer count
                yt[(r0 + rg) * 128 + wn * 64 + in * 16 + l15] = (short)vi;
                float v = (float)vi;
                s1 += v;
                s2 += v * v;
            }
        }
        s1 += __shfl_xor(s1, 16); s2 += __shfl_xor(s2, 16);
        s1 += __shfl_xor(s1, 32); s2 += __shfl_xor(s2, 32);
        if (lhi == 0) {
            atomicAdd(&bnsum[o], s1);
            atomicAdd(&bnsumsq[o], s2);
        }
    }
    __syncthreads();
    // coalesced NHWC stores: 16 threads x 16B = one 128-cout half-row
#pragma unroll
    for (int pass = 0; pass < 8; ++pass) {
        int p = (tid >> 4) + 16 * pass;
        int c = tid & 15;
        *(short8*)&y[(size_t)(mt * 128 + p) * COUT + nt * 128 + c * 8] =
            *(const short8*)&yt[p * 128 + c * 8];
    }
}

// ---------------------------------------------------------------------------
// Kernel 3: int16 NHWC -> fp32 NCHW transpose + affine + relu.
// R6 v2: full-256-channel blocks, grid (49, 32). All 8 short8 loads issued
// UP FRONT (128 B/thread in flight — 4x the old MLP); per-channel BN coeffs
// for all 256 channels computed once into LDS (1 thread = 1 channel); then
// 4 sequential 64-ch transpose panels through one 16.6 KB LDS buffer.
// Loads stay in flight across the coeff phase + first barrier.
// ---------------------------------------------------------------------------
__global__ __launch_bounds__(256) void bn_out(const short* __restrict__ y,
                                              const float* __restrict__ bnsum,
                                              const float* __restrict__ bnsumsq,
                                              const float* __restrict__ scale,
                                              const float* __restrict__ gamma,
                                              const float* __restrict__ beta,
                                              float* __restrict__ out) {
    __shared__ float lds[64 * 65];   // [pix][ch-in-panel], stride 65
    __shared__ float gs[256], cs[256];
    int p0 = blockIdx.x * 64;
    int n  = blockIdx.y;
    int t  = threadIdx.x;

    // issue all y loads first (8 x short8 = 128 B/thread in flight)
    int cch = t & 7;               // 16B chunk within a 64-ch panel
    int piA = t >> 3;              // pixel 0..31
    const short* yb = y + ((size_t)n * HW + p0) * COUT;
    short8 sv[4][2];
#pragma unroll
    for (int g = 0; g < 4; ++g)
#pragma unroll
        for (int j = 0; j < 2; ++j)
            sv[g][j] = *(const short8*)&yb[(size_t)(piA + 32 * j) * COUT + g * 64 + cch * 8];

    // per-channel coefficients (1 thread = 1 channel), overlaps load latency
    {
        float mean = bnsum[t] * (1.f / (float)NPIX);
        float var  = fmaxf(bnsumsq[t] * (1.f / (float)NPIX) - mean * mean, 0.f);
        float sc   = scale[t];
        float inv  = rsqrtf(sc * sc * var + 1e-5f);
        float g    = gamma[t] * sc * inv;
        gs[t] = g;
        cs[t] = beta[t] - mean * g;
    }
    __syncthreads();

#pragma unroll
    for (int g = 0; g < 4; ++g) {
        int o0 = g * 64;
#pragma unroll
        for (int j = 0; j < 2; ++j) {
            int pi = piA + 32 * j;
#pragma unroll
            for (int e = 0; e < 8; ++e) {
                int ch = o0 + cch * 8 + e;
                lds[pi * 65 + cch * 8 + e] =
                    fmaxf(gs[ch] * (float)sv[g][j][e] + cs[ch], 0.f);
            }
        }
        __syncthreads();
        float* ob = out + ((size_t)n * COUT + o0) * HW + p0;
        int pq = t & 15;       // 16 float4 = 64 pixels
        int ch = t >> 4;       // 16 channels per round
#pragma unroll
        for (int r = 0; r < 4; ++r) {
            int cr = ch + 16 * r;
            floatx4 v;
#pragma unroll
            for (int e = 0; e < 4; ++e) v[e] = lds[(pq * 4 + e) * 65 + cr];
            *(floatx4*)&ob[(size_t)cr * HW + pq * 4] = v;
        }
        if (g < 3) __syncthreads();   // WAR before next panel overwrites lds
    }
}

// ---------------------------------------------------------------------------
extern "C" void kernel_launch(void* const* d_in, const int* in_sizes, int n_in,
                              void* d_out, int out_size, void* d_ws, size_t ws_size,
                              hipStream_t stream) {
    const float* x     = (const float*)d_in[0];   // [32,256,56,56]
    const float* w     = (const float*)d_in[1];   // [256,256,3,3]
    const float* gamma = (const float*)d_in[2];   // [256]
    const float* beta  = (const float*)d_in[3];   // [256]
    float* out = (float*)d_out;

    char* ws = (char*)d_ws;
    size_t off = 0;
    i8* xs = (i8*)(ws + off);    off += (size_t)BATCH * PPIX * CIN;                // 27.6 MB
    i8* wg = (i8*)(ws + off);    off += (size_t)COUT * KTOT;                       // 0.59 MB
    short* y = (short*)(ws + off); off += (size_t)NPIX * COUT * sizeof(short);     // 51.4 MB
    float* scale   = (float*)(ws + off); off += 1024;
    float* bnsum   = (float*)(ws + off); off += 1024;
    float* bnsumsq = (float*)(ws + off); off += 1024;

    hipLaunchKernelGGL(front, dim3(NBIN + COUT + NBRD), dim3(256), 0, stream,
                       x, w, xs, wg, scale, bnsum, bnsumsq);
    hipLaunchKernelGGL(conv_gemm, dim3(NPIX / 128 * 2), dim3(256), 0, stream,
                       xs, wg, y, bnsum, bnsumsq);
    hipLaunchKernelGGL(bn_out, dim3(HW / 64, BATCH), dim3(256), 0, stream,
                       y, bnsum, bnsumsq, scale, gamma, beta, out);
}